// Round 1
// baseline (2454.648 us; speedup 1.0000x reference)
//
#include <hip/hip_runtime.h>
#include <hip/hip_bf16.h>

// Problem constants (from reference)
#define NB      100000    // B*N nodes
#define NPB     25000     // N per batch
#define T_E     800000    // B*E total edges
#define EPG     200000    // E per graph
#define DMODEL  128       // OUT = H*DH
#define EDIM    32
#define FFD     256

// -------------------------------------------------------------------------
// Kernel 1: node projections q,k,v and skip (written into agg as its init),
// plus zeroing of denom.  64 nodes per 256-thread block.
// -------------------------------------------------------------------------
__global__ __launch_bounds__(256) void k_proj(
    const float* __restrict__ x,
    const float* __restrict__ Wq, const float* __restrict__ bq,
    const float* __restrict__ Wk, const float* __restrict__ bk,
    const float* __restrict__ Wv, const float* __restrict__ bv,
    const float* __restrict__ Wskip, const float* __restrict__ bskip,
    float* __restrict__ qb, float* __restrict__ kb, float* __restrict__ vb,
    float* __restrict__ agg, float* __restrict__ denom)
{
    __shared__ float xs[64][132];   // +4 pad: conflict-free & 16B-aligned rows
    const int tid   = threadIdx.x;
    const int node0 = blockIdx.x * 64;

    // Stage xf tile: x[b,c,n] -> xs[n][c]; consecutive tid = consecutive n.
    for (int it = 0; it < 32; ++it) {
        int linear = it * 256 + tid;
        int n = linear & 63;
        int c = linear >> 6;
        int node = node0 + n;
        float v = 0.f;
        if (node < NB) {
            int b  = node / NPB;
            int nn = node - b * NPB;
            v = x[((size_t)(b * DMODEL + c)) * NPB + nn];
        }
        xs[n][c] = v;
    }
    // zero denom (64 nodes * 4 heads = 256 entries)
    {
        int node = node0 + (tid >> 2);
        if (node < NB) denom[node * 4 + (tid & 3)] = 0.f;
    }
    __syncthreads();

    const int c     = tid & 127;
    const int jbase = (tid >> 7) * 32;
    float wreg[128];

#define DO_MAT(W, BIAS, OUTP)                                            \
    {                                                                    \
        _Pragma("unroll")                                                \
        for (int k = 0; k < 128; ++k) wreg[k] = W[k * DMODEL + c];       \
        const float bias_ = BIAS[c];                                     \
        for (int j = 0; j < 32; ++j) {                                   \
            int node = node0 + jbase + j;                                \
            float acc = bias_;                                           \
            const float4* xr = (const float4*)xs[jbase + j];             \
            _Pragma("unroll")                                            \
            for (int k4 = 0; k4 < 32; ++k4) {                            \
                float4 xv = xr[k4];                                      \
                acc += xv.x * wreg[4 * k4 + 0] + xv.y * wreg[4 * k4 + 1] \
                     + xv.z * wreg[4 * k4 + 2] + xv.w * wreg[4 * k4 + 3];\
            }                                                            \
            if (node < NB) OUTP[(size_t)node * DMODEL + c] = acc;        \
        }                                                                \
    }

    DO_MAT(Wq, bq, qb)
    DO_MAT(Wk, bk, kb)
    DO_MAT(Wv, bv, vb)
    DO_MAT(Wskip, bskip, agg)
#undef DO_MAT
}

// -------------------------------------------------------------------------
// Kernel 2: per-edge alpha -> ea = exp(alpha*scale), denom via atomics.
// 64 edges per block; 128 lanes per edge slot (2 slots in flight).
// -------------------------------------------------------------------------
__global__ __launch_bounds__(256) void k_alpha(
    const float* __restrict__ qb, const float* __restrict__ kb,
    const int*   __restrict__ eidx, const float* __restrict__ eattr,
    const float* __restrict__ We,
    float* __restrict__ ea_buf, float* __restrict__ denom)
{
    __shared__ float eas[64][36];
    __shared__ int   srcs[64], dsts[64];
    const int tid = threadIdx.x;
    const int t0  = blockIdx.x * 64;
    const int c   = tid & 127;

    float wer[32];
#pragma unroll
    for (int k = 0; k < EDIM; ++k) wer[k] = We[k * DMODEL + c];

    // stage 64 edges' attrs (fully coalesced: contiguous 2048 floats)
#pragma unroll
    for (int it = 0; it < 8; ++it) {
        int linear = it * 256 + tid;
        eas[linear >> 5][linear & 31] = eattr[(size_t)t0 * EDIM + linear];
    }
    if (tid < 64) {
        int t = t0 + tid;
        int b = t / EPG;
        int e = t - b * EPG;
        srcs[tid] = eidx[(size_t)(b * 2) * EPG + e];
        dsts[tid] = eidx[(size_t)(b * 2 + 1) * EPG + e];
    }
    __syncthreads();

    const int g = tid >> 7;
    const int h = c >> 5;
    const int d = c & 31;

    for (int sub = 0; sub < 32; ++sub) {
        int slot = sub * 2 + g;
        int t = t0 + slot;
        float eacc = 0.f;
        const float4* er = (const float4*)eas[slot];
#pragma unroll
        for (int k4 = 0; k4 < 8; ++k4) {
            float4 ev = er[k4];
            eacc += ev.x * wer[4 * k4 + 0] + ev.y * wer[4 * k4 + 1]
                  + ev.z * wer[4 * k4 + 2] + ev.w * wer[4 * k4 + 3];
        }
        int sv = srcs[slot], dv = dsts[slot];
        float qv = qb[(size_t)dv * DMODEL + c];
        float kv = kb[(size_t)sv * DMODEL + c];
        float p = qv * (kv + eacc);
#pragma unroll
        for (int off = 16; off >= 1; off >>= 1) p += __shfl_xor(p, off, 64);
        float ea = __expf(p * 0.17677669529663689f);  // 1/sqrt(32)
        if (d == 0) {
            ea_buf[(size_t)t * 4 + h] = ea;
            unsafeAtomicAdd(&denom[dv * 4 + h], ea);
        }
    }
}

// -------------------------------------------------------------------------
// Kernel 3: per-edge weighted aggregation of (v[src]+e) into agg via atomics.
// -------------------------------------------------------------------------
__global__ __launch_bounds__(256) void k_aggr(
    const float* __restrict__ vb,
    const int*   __restrict__ eidx, const float* __restrict__ eattr,
    const float* __restrict__ We,
    const float* __restrict__ ea_buf, const float* __restrict__ denom,
    float* __restrict__ agg)
{
    __shared__ float eas[64][36];
    __shared__ int   srcs[64], dsts[64];
    const int tid = threadIdx.x;
    const int t0  = blockIdx.x * 64;
    const int c   = tid & 127;

    float wer[32];
#pragma unroll
    for (int k = 0; k < EDIM; ++k) wer[k] = We[k * DMODEL + c];

#pragma unroll
    for (int it = 0; it < 8; ++it) {
        int linear = it * 256 + tid;
        eas[linear >> 5][linear & 31] = eattr[(size_t)t0 * EDIM + linear];
    }
    if (tid < 64) {
        int t = t0 + tid;
        int b = t / EPG;
        int e = t - b * EPG;
        srcs[tid] = eidx[(size_t)(b * 2) * EPG + e];
        dsts[tid] = eidx[(size_t)(b * 2 + 1) * EPG + e];
    }
    __syncthreads();

    const int g = tid >> 7;
    const int h = c >> 5;

    for (int sub = 0; sub < 32; ++sub) {
        int slot = sub * 2 + g;
        int t = t0 + slot;
        float eacc = 0.f;
        const float4* er = (const float4*)eas[slot];
#pragma unroll
        for (int k4 = 0; k4 < 8; ++k4) {
            float4 ev = er[k4];
            eacc += ev.x * wer[4 * k4 + 0] + ev.y * wer[4 * k4 + 1]
                  + ev.z * wer[4 * k4 + 2] + ev.w * wer[4 * k4 + 3];
        }
        int sv = srcs[slot], dv = dsts[slot];
        float ea  = ea_buf[(size_t)t * 4 + h];
        float den = denom[dv * 4 + h];
        float w = ea / (den + 1e-16f);
        float vv = vb[(size_t)sv * DMODEL + c] + eacc;
        unsafeAtomicAdd(&agg[(size_t)dv * DMODEL + c], w * vv);
    }
}

// -------------------------------------------------------------------------
// Kernel 4: FFN (128 -> 256 relu -> 128 relu) + transposed output write.
// 32 nodes per 256-thread block.
// -------------------------------------------------------------------------
__global__ __launch_bounds__(256) void k_ffn(
    const float* __restrict__ agg,
    const float* __restrict__ W1, const float* __restrict__ b1,
    const float* __restrict__ W2, const float* __restrict__ b2,
    float* __restrict__ out)
{
    __shared__ float outs[32][132];
    __shared__ float h1s[32][260];
    const int tid   = threadIdx.x;
    const int node0 = blockIdx.x * 32;

    // stage A: load out = agg (skip already folded in)
#pragma unroll
    for (int it = 0; it < 16; ++it) {
        int linear = it * 256 + tid;
        int nj = linear >> 7, cc = linear & 127;
        int node = node0 + nj;
        outs[nj][cc] = (node < NB) ? agg[(size_t)node * DMODEL + cc] : 0.f;
    }
    __syncthreads();

    float wreg[128];
    // stage B: h1 = relu(out @ W1 + b1); thread owns W1 column tid (0..255)
    {
        const int c = tid;
#pragma unroll
        for (int k = 0; k < 128; ++k) wreg[k] = W1[k * FFD + c];
        const float bias_ = b1[c];
        for (int j = 0; j < 32; ++j) {
            float acc = bias_;
            const float4* xr = (const float4*)outs[j];
#pragma unroll
            for (int k4 = 0; k4 < 32; ++k4) {
                float4 xv = xr[k4];
                acc += xv.x * wreg[4 * k4 + 0] + xv.y * wreg[4 * k4 + 1]
                     + xv.z * wreg[4 * k4 + 2] + xv.w * wreg[4 * k4 + 3];
            }
            h1s[j][c] = fmaxf(acc, 0.f);
        }
    }
    __syncthreads();

    // stage C: h = relu(h1 @ W2 + b2); thread (c2, jh) does 16 nodes
    const int c2 = tid & 127;
    const int jh = tid >> 7;
    float acc2[16];
#pragma unroll
    for (int j = 0; j < 16; ++j) acc2[j] = b2[c2];
    for (int half = 0; half < 2; ++half) {
#pragma unroll
        for (int k = 0; k < 128; ++k) wreg[k] = W2[(half * 128 + k) * DMODEL + c2];
        for (int j = 0; j < 16; ++j) {
            const float4* hr = (const float4*)&h1s[jh * 16 + j][half * 128];
            float a = acc2[j];
#pragma unroll
            for (int k4 = 0; k4 < 32; ++k4) {
                float4 xv = hr[k4];
                a += xv.x * wreg[4 * k4 + 0] + xv.y * wreg[4 * k4 + 1]
                   + xv.z * wreg[4 * k4 + 2] + xv.w * wreg[4 * k4 + 3];
            }
            acc2[j] = a;
        }
    }
    // stage D: write h back into outs (reuse) — safe: stage-B readers passed barrier
    for (int j = 0; j < 16; ++j) outs[jh * 16 + j][c2] = fmaxf(acc2[j], 0.f);
    __syncthreads();

    // stage E: transposed write out[b, c, n]
#pragma unroll
    for (int it = 0; it < 16; ++it) {
        int linear = it * 256 + tid;
        int cc = linear >> 5;
        int jj = linear & 31;
        int node = node0 + jj;
        if (node < NB) {
            int b  = node / NPB;
            int nn = node - b * NPB;
            out[((size_t)(b * DMODEL + cc)) * NPB + nn] = outs[jj][cc];
        }
    }
}

// -------------------------------------------------------------------------
extern "C" void kernel_launch(void* const* d_in, const int* in_sizes, int n_in,
                              void* d_out, int out_size, void* d_ws, size_t ws_size,
                              hipStream_t stream)
{
    const float* x     = (const float*)d_in[0];
    const int*   eidx  = (const int*)  d_in[1];
    const float* eattr = (const float*)d_in[2];
    const float* Wq    = (const float*)d_in[3];
    const float* bq    = (const float*)d_in[4];
    const float* Wk    = (const float*)d_in[5];
    const float* bk    = (const float*)d_in[6];
    const float* Wv    = (const float*)d_in[7];
    const float* bv    = (const float*)d_in[8];
    const float* We    = (const float*)d_in[9];
    const float* Wskip = (const float*)d_in[10];
    const float* bskip = (const float*)d_in[11];
    const float* W1    = (const float*)d_in[12];
    const float* b1    = (const float*)d_in[13];
    const float* W2    = (const float*)d_in[14];
    const float* b2    = (const float*)d_in[15];
    float* out = (float*)d_out;

    // workspace layout (floats): q | k | v | agg | ea | denom  = 219.2 MB
    float* ws    = (float*)d_ws;
    float* qb    = ws;
    float* kb    = qb + (size_t)NB * DMODEL;
    float* vb    = kb + (size_t)NB * DMODEL;
    float* agg   = vb + (size_t)NB * DMODEL;
    float* ea_bf = agg + (size_t)NB * DMODEL;
    float* denom = ea_bf + (size_t)T_E * 4;

    k_proj<<<(NB + 63) / 64, 256, 0, stream>>>(x, Wq, bq, Wk, bk, Wv, bv,
                                               Wskip, bskip, qb, kb, vb, agg, denom);
    k_alpha<<<T_E / 64, 256, 0, stream>>>(qb, kb, eidx, eattr, We, ea_bf, denom);
    k_aggr<<<T_E / 64, 256, 0, stream>>>(vb, eidx, eattr, We, ea_bf, denom, agg);
    k_ffn<<<(NB + 31) / 32, 256, 0, stream>>>(agg, W1, b1, W2, b2, out);
}

// Round 3
// 1362.753 us; speedup vs baseline: 1.8012x; 1.8012x over previous
//
#include <hip/hip_runtime.h>
#include <hip/hip_bf16.h>

// Problem constants (from reference)
#define NB      100000    // B*N nodes
#define NPB     25000     // N per batch
#define T_E     800000    // B*E total edges
#define EPG     200000    // E per graph
#define DMODEL  128       // OUT = H*DH
#define EDIM    32
#define FFD     256

typedef __attribute__((ext_vector_type(8))) short bf16x8;
typedef __attribute__((ext_vector_type(4))) float f32x4;

__device__ inline unsigned short f2bf(float f) {
    unsigned u = __float_as_uint(f);
    unsigned r = u + 0x7fffu + ((u >> 16) & 1u);   // RNE
    return (unsigned short)(r >> 16);
}
__device__ inline unsigned pack_bf16x2(float lo, float hi) {
    return (unsigned)f2bf(lo) | ((unsigned)f2bf(hi) << 16);
}

// -------------------------------------------------------------------------
// Kernel 1 (MFMA): node projections. blockIdx.y selects matrix
// (0=Q,1=K,2=V,3=skip->agg). 128 nodes per block, 256 threads = 4 waves.
// LDS: xs [128 nodes][128 c] bf16 XOR-swizzled @0 (32KB),
//      wt [128 cols ][128 c] bf16 XOR-swizzled @32768 (32KB).
// -------------------------------------------------------------------------
#define XS_OFF 0
#define WT_OFF 32768

__global__ __launch_bounds__(256) void k_proj_mfma(
    const float* __restrict__ x,
    const float* __restrict__ Wq, const float* __restrict__ bq,
    const float* __restrict__ Wk, const float* __restrict__ bk,
    const float* __restrict__ Wv, const float* __restrict__ bv,
    const float* __restrict__ Wskip, const float* __restrict__ bskip,
    float* __restrict__ qb, float* __restrict__ kb, float* __restrict__ vb,
    float* __restrict__ agg, float* __restrict__ denom)
{
    __shared__ __align__(16) char lds[65536];
    const int tid   = threadIdx.x;
    const int m     = blockIdx.y;
    const int node0 = blockIdx.x * 128;

    const float* W   = (m == 0) ? Wq : (m == 1) ? Wk : (m == 2) ? Wv : Wskip;
    const float* bi  = (m == 0) ? bq : (m == 1) ? bk : (m == 2) ? bv : bskip;
    float*       outp= (m == 0) ? qb : (m == 1) ? kb : (m == 2) ? vb : agg;

    // ---- stage xs: x[b,c,nn] -> xs[node_local][c] (bf16, swizzled)
    {
        const int nl   = tid & 127;
        const int half = tid >> 7;
        const int node = node0 + nl;
        const bool valid = node < NB;
        int b  = node / NPB;
        int nn = node - b * NPB;
        const float* xbase = x + (size_t)b * DMODEL * NPB + nn;
#pragma unroll
        for (int o = 0; o < 8; ++o) {
            int c0 = (o * 2 + half) * 8;       // octet of 8 channels
            unsigned vals[4];
#pragma unroll
            for (int j2 = 0; j2 < 4; ++j2) {
                float f0 = valid ? xbase[(size_t)(c0 + 2 * j2) * NPB] : 0.f;
                float f1 = valid ? xbase[(size_t)(c0 + 2 * j2 + 1) * NPB] : 0.f;
                vals[j2] = pack_bf16x2(f0, f1);
            }
            int byte = nl * 256 + ((c0 * 2) ^ ((nl & 7) << 4));
            *(uint4*)(&lds[XS_OFF + byte]) = make_uint4(vals[0], vals[1], vals[2], vals[3]);
        }
    }
    // ---- stage wt: W[c,col] -> wt[col][c] (bf16, swizzled)
    {
        const int col  = tid & 127;
        const int half = tid >> 7;
#pragma unroll
        for (int o = 0; o < 8; ++o) {
            int c0 = (o * 2 + half) * 8;
            unsigned vals[4];
#pragma unroll
            for (int j2 = 0; j2 < 4; ++j2) {
                float f0 = W[(size_t)(c0 + 2 * j2) * DMODEL + col];
                float f1 = W[(size_t)(c0 + 2 * j2 + 1) * DMODEL + col];
                vals[j2] = pack_bf16x2(f0, f1);
            }
            int byte = col * 256 + ((c0 * 2) ^ ((col & 7) << 4));
            *(uint4*)(&lds[WT_OFF + byte]) = make_uint4(vals[0], vals[1], vals[2], vals[3]);
        }
    }
    // denom zero (only the m==0 grid slice)
    if (m == 0) {
#pragma unroll
        for (int i = 0; i < 2; ++i) {
            int idx  = i * 256 + tid;          // 0..511
            int node = node0 + (idx >> 2);
            if (node < NB) denom[node * 4 + (idx & 3)] = 0.f;
        }
    }
    __syncthreads();

    // ---- MFMA: wave w computes nodes [w*32, w*32+32) x all 128 cols
    const int w    = tid >> 6;
    const int lane = tid & 63;
    const int rl   = lane & 15;
    const int g    = lane >> 4;

    f32x4 acc[2][8] = {};
#pragma unroll
    for (int ks = 0; ks < 4; ++ks) {
        const int kb2 = ks * 64 + g * 16;      // byte offset of this lane's k-octet
        bf16x8 a[2], b[8];
#pragma unroll
        for (int mt = 0; mt < 2; ++mt) {
            int row = w * 32 + mt * 16 + rl;
            a[mt] = *(const bf16x8*)(&lds[XS_OFF + row * 256 + (kb2 ^ ((row & 7) << 4))]);
        }
#pragma unroll
        for (int nt = 0; nt < 8; ++nt) {
            int colr = nt * 16 + rl;
            b[nt] = *(const bf16x8*)(&lds[WT_OFF + colr * 256 + (kb2 ^ ((colr & 7) << 4))]);
        }
#pragma unroll
        for (int mt = 0; mt < 2; ++mt)
#pragma unroll
            for (int nt = 0; nt < 8; ++nt)
                acc[mt][nt] = __builtin_amdgcn_mfma_f32_16x16x32_bf16(
                    a[mt], b[nt], acc[mt][nt], 0, 0, 0);
    }

    // ---- epilogue: D col = lane&15, row = (lane>>4)*4 + r  (m91-verified)
#pragma unroll
    for (int mt = 0; mt < 2; ++mt) {
        int nodeb = node0 + w * 32 + mt * 16 + g * 4;
#pragma unroll
        for (int nt = 0; nt < 8; ++nt) {
            int col = nt * 16 + rl;
            float bv_ = bi[col];
#pragma unroll
            for (int r = 0; r < 4; ++r) {
                int node = nodeb + r;
                if (node < NB) outp[(size_t)node * DMODEL + col] = acc[mt][nt][r] + bv_;
            }
        }
    }
}

// -------------------------------------------------------------------------
// Kernel 2: per-edge alpha -> ea = exp(alpha*scale), denom via atomics.
// -------------------------------------------------------------------------
__global__ __launch_bounds__(256) void k_alpha(
    const float* __restrict__ qb, const float* __restrict__ kb,
    const int*   __restrict__ eidx, const float* __restrict__ eattr,
    const float* __restrict__ We,
    float* __restrict__ ea_buf, float* __restrict__ denom)
{
    __shared__ float eas[64][36];
    __shared__ int   srcs[64], dsts[64];
    const int tid = threadIdx.x;
    const int t0  = blockIdx.x * 64;
    const int c   = tid & 127;

    float wer[32];
#pragma unroll
    for (int k = 0; k < EDIM; ++k) wer[k] = We[k * DMODEL + c];

#pragma unroll
    for (int it = 0; it < 8; ++it) {
        int linear = it * 256 + tid;
        eas[linear >> 5][linear & 31] = eattr[(size_t)t0 * EDIM + linear];
    }
    if (tid < 64) {
        int t = t0 + tid;
        int b = t / EPG;
        int e = t - b * EPG;
        srcs[tid] = eidx[(size_t)(b * 2) * EPG + e];
        dsts[tid] = eidx[(size_t)(b * 2 + 1) * EPG + e];
    }
    __syncthreads();

    const int g = tid >> 7;
    const int h = c >> 5;
    const int d = c & 31;

    for (int sub = 0; sub < 32; ++sub) {
        int slot = sub * 2 + g;
        int t = t0 + slot;
        float eacc = 0.f;
        const float4* er = (const float4*)eas[slot];
#pragma unroll
        for (int k4 = 0; k4 < 8; ++k4) {
            float4 ev = er[k4];
            eacc += ev.x * wer[4 * k4 + 0] + ev.y * wer[4 * k4 + 1]
                  + ev.z * wer[4 * k4 + 2] + ev.w * wer[4 * k4 + 3];
        }
        int sv = srcs[slot], dv = dsts[slot];
        float qv = qb[(size_t)dv * DMODEL + c];
        float kv = kb[(size_t)sv * DMODEL + c];
        float p = qv * (kv + eacc);
#pragma unroll
        for (int off = 16; off >= 1; off >>= 1) p += __shfl_xor(p, off, 64);
        float ea = __expf(p * 0.17677669529663689f);  // 1/sqrt(32)
        if (d == 0) {
            ea_buf[(size_t)t * 4 + h] = ea;
            unsafeAtomicAdd(&denom[dv * 4 + h], ea);
        }
    }
}

// -------------------------------------------------------------------------
// Kernel 3: per-edge weighted aggregation of (v[src]+e) into agg via atomics.
// -------------------------------------------------------------------------
__global__ __launch_bounds__(256) void k_aggr(
    const float* __restrict__ vb,
    const int*   __restrict__ eidx, const float* __restrict__ eattr,
    const float* __restrict__ We,
    const float* __restrict__ ea_buf, const float* __restrict__ denom,
    float* __restrict__ agg)
{
    __shared__ float eas[64][36];
    __shared__ int   srcs[64], dsts[64];
    const int tid = threadIdx.x;
    const int t0  = blockIdx.x * 64;
    const int c   = tid & 127;

    float wer[32];
#pragma unroll
    for (int k = 0; k < EDIM; ++k) wer[k] = We[k * DMODEL + c];

#pragma unroll
    for (int it = 0; it < 8; ++it) {
        int linear = it * 256 + tid;
        eas[linear >> 5][linear & 31] = eattr[(size_t)t0 * EDIM + linear];
    }
    if (tid < 64) {
        int t = t0 + tid;
        int b = t / EPG;
        int e = t - b * EPG;
        srcs[tid] = eidx[(size_t)(b * 2) * EPG + e];
        dsts[tid] = eidx[(size_t)(b * 2 + 1) * EPG + e];
    }
    __syncthreads();

    const int g = tid >> 7;
    const int h = c >> 5;

    for (int sub = 0; sub < 32; ++sub) {
        int slot = sub * 2 + g;
        int t = t0 + slot;
        float eacc = 0.f;
        const float4* er = (const float4*)eas[slot];
#pragma unroll
        for (int k4 = 0; k4 < 8; ++k4) {
            float4 ev = er[k4];
            eacc += ev.x * wer[4 * k4 + 0] + ev.y * wer[4 * k4 + 1]
                  + ev.z * wer[4 * k4 + 2] + ev.w * wer[4 * k4 + 3];
        }
        int sv = srcs[slot], dv = dsts[slot];
        float ea  = ea_buf[(size_t)t * 4 + h];
        float den = denom[dv * 4 + h];
        float w = ea / (den + 1e-16f);
        float vv = vb[(size_t)sv * DMODEL + c] + eacc;
        unsafeAtomicAdd(&agg[(size_t)dv * DMODEL + c], w * vv);
    }
}

// -------------------------------------------------------------------------
// Kernel 4: FFN (128 -> 256 relu -> 128 relu) + transposed output write.
// 32 nodes per 256-thread block.  4-way split accumulators (ILP fix).
// -------------------------------------------------------------------------
__global__ __launch_bounds__(256) void k_ffn(
    const float* __restrict__ agg,
    const float* __restrict__ W1, const float* __restrict__ b1,
    const float* __restrict__ W2, const float* __restrict__ b2,
    float* __restrict__ out)
{
    __shared__ float outs[32][132];
    __shared__ float h1s[32][260];
    const int tid   = threadIdx.x;
    const int node0 = blockIdx.x * 32;

#pragma unroll
    for (int it = 0; it < 16; ++it) {
        int linear = it * 256 + tid;
        int nj = linear >> 7, cc = linear & 127;
        int node = node0 + nj;
        outs[nj][cc] = (node < NB) ? agg[(size_t)node * DMODEL + cc] : 0.f;
    }
    __syncthreads();

    float wreg[128];
    // stage B: h1 = relu(out @ W1 + b1); thread owns W1 column tid (0..255)
    {
        const int c = tid;
#pragma unroll
        for (int k = 0; k < 128; ++k) wreg[k] = W1[k * FFD + c];
        const float bias_ = b1[c];
        for (int j = 0; j < 32; ++j) {
            float a0 = bias_, a1 = 0.f, a2 = 0.f, a3 = 0.f;
            const float4* xr = (const float4*)outs[j];
#pragma unroll
            for (int k4 = 0; k4 < 32; ++k4) {
                float4 xv = xr[k4];
                a0 += xv.x * wreg[4 * k4 + 0];
                a1 += xv.y * wreg[4 * k4 + 1];
                a2 += xv.z * wreg[4 * k4 + 2];
                a3 += xv.w * wreg[4 * k4 + 3];
            }
            h1s[j][c] = fmaxf((a0 + a1) + (a2 + a3), 0.f);
        }
    }
    __syncthreads();

    // stage C: h = relu(h1 @ W2 + b2); thread (c2, jh) does 16 nodes
    const int c2 = tid & 127;
    const int jh = tid >> 7;
    float acc2[16];
#pragma unroll
    for (int j = 0; j < 16; ++j) acc2[j] = b2[c2];
    for (int half = 0; half < 2; ++half) {
#pragma unroll
        for (int k = 0; k < 128; ++k) wreg[k] = W2[(half * 128 + k) * DMODEL + c2];
        for (int j = 0; j < 16; ++j) {
            const float4* hr = (const float4*)&h1s[jh * 16 + j][half * 128];
            float p0 = 0.f, p1 = 0.f, p2 = 0.f, p3 = 0.f;
#pragma unroll
            for (int k4 = 0; k4 < 32; ++k4) {
                float4 xv = hr[k4];
                p0 += xv.x * wreg[4 * k4 + 0];
                p1 += xv.y * wreg[4 * k4 + 1];
                p2 += xv.z * wreg[4 * k4 + 2];
                p3 += xv.w * wreg[4 * k4 + 3];
            }
            acc2[j] += (p0 + p1) + (p2 + p3);
        }
    }
    for (int j = 0; j < 16; ++j) outs[jh * 16 + j][c2] = fmaxf(acc2[j], 0.f);
    __syncthreads();

    // transposed write out[b, c, n]
#pragma unroll
    for (int it = 0; it < 16; ++it) {
        int linear = it * 256 + tid;
        int cc = linear >> 5;
        int jj = linear & 31;
        int node = node0 + jj;
        if (node < NB) {
            int b  = node / NPB;
            int nn = node - b * NPB;
            out[((size_t)(b * DMODEL + cc)) * NPB + nn] = outs[jj][cc];
        }
    }
}

// -------------------------------------------------------------------------
extern "C" void kernel_launch(void* const* d_in, const int* in_sizes, int n_in,
                              void* d_out, int out_size, void* d_ws, size_t ws_size,
                              hipStream_t stream)
{
    const float* x     = (const float*)d_in[0];
    const int*   eidx  = (const int*)  d_in[1];
    const float* eattr = (const float*)d_in[2];
    const float* Wq    = (const float*)d_in[3];
    const float* bq    = (const float*)d_in[4];
    const float* Wk    = (const float*)d_in[5];
    const float* bk    = (const float*)d_in[6];
    const float* Wv    = (const float*)d_in[7];
    const float* bv    = (const float*)d_in[8];
    const float* We    = (const float*)d_in[9];
    const float* Wskip = (const float*)d_in[10];
    const float* bskip = (const float*)d_in[11];
    const float* W1    = (const float*)d_in[12];
    const float* b1    = (const float*)d_in[13];
    const float* W2    = (const float*)d_in[14];
    const float* b2    = (const float*)d_in[15];
    float* out = (float*)d_out;

    float* ws    = (float*)d_ws;
    float* qb    = ws;
    float* kb    = qb + (size_t)NB * DMODEL;
    float* vb    = kb + (size_t)NB * DMODEL;
    float* agg   = vb + (size_t)NB * DMODEL;
    float* ea_bf = agg + (size_t)NB * DMODEL;
    float* denom = ea_bf + (size_t)T_E * 4;

    dim3 pgrid((NB + 127) / 128, 4);
    k_proj_mfma<<<pgrid, 256, 0, stream>>>(x, Wq, bq, Wk, bk, Wv, bv,
                                           Wskip, bskip, qb, kb, vb, agg, denom);
    k_alpha<<<T_E / 64, 256, 0, stream>>>(qb, kb, eidx, eattr, We, ea_bf, denom);
    k_aggr<<<T_E / 64, 256, 0, stream>>>(vb, eidx, eattr, We, ea_bf, denom, agg);
    k_ffn<<<(NB + 31) / 32, 256, 0, stream>>>(agg, W1, b1, W2, b2, out);
}

// Round 4
// 695.471 us; speedup vs baseline: 3.5295x; 1.9595x over previous
//
#include <hip/hip_runtime.h>
#include <hip/hip_bf16.h>

// Problem constants (from reference)
#define NB      100000    // B*N nodes
#define NPB     25000     // N per batch
#define T_E     800000    // B*E total edges
#define EPG     200000    // E per graph
#define DMODEL  128       // OUT = H*DH
#define EDIM    32
#define FFD     256

typedef __attribute__((ext_vector_type(8))) short bf16x8;
typedef __attribute__((ext_vector_type(4))) float f32x4;

__device__ inline unsigned short f2bf(float f) {
    unsigned u = __float_as_uint(f);
    unsigned r = u + 0x7fffu + ((u >> 16) & 1u);   // RNE
    return (unsigned short)(r >> 16);
}
__device__ inline unsigned pack_bf16x2(float lo, float hi) {
    return (unsigned)f2bf(lo) | ((unsigned)f2bf(hi) << 16);
}

// -------------------------------------------------------------------------
// Kernel 1 (MFMA): node projections. blockIdx.y selects matrix
// (0=Q,1=K,2=V,3=skip->agg). 128 nodes per block, 256 threads = 4 waves.
// -------------------------------------------------------------------------
#define XS_OFF 0
#define WT_OFF 32768

__global__ __launch_bounds__(256) void k_proj_mfma(
    const float* __restrict__ x,
    const float* __restrict__ Wq, const float* __restrict__ bq,
    const float* __restrict__ Wk, const float* __restrict__ bk,
    const float* __restrict__ Wv, const float* __restrict__ bv,
    const float* __restrict__ Wskip, const float* __restrict__ bskip,
    float* __restrict__ qb, float* __restrict__ kb, float* __restrict__ vb,
    float* __restrict__ agg, float* __restrict__ denom)
{
    __shared__ __align__(16) char lds[65536];
    const int tid   = threadIdx.x;
    const int m     = blockIdx.y;
    const int node0 = blockIdx.x * 128;

    const float* W   = (m == 0) ? Wq : (m == 1) ? Wk : (m == 2) ? Wv : Wskip;
    const float* bi  = (m == 0) ? bq : (m == 1) ? bk : (m == 2) ? bv : bskip;
    float*       outp= (m == 0) ? qb : (m == 1) ? kb : (m == 2) ? vb : agg;

    // ---- stage xs: x[b,c,nn] -> xs[node_local][c] (bf16, swizzled)
    {
        const int nl   = tid & 127;
        const int half = tid >> 7;
        const int node = node0 + nl;
        const bool valid = node < NB;
        int b  = node / NPB;
        int nn = node - b * NPB;
        const float* xbase = x + (size_t)b * DMODEL * NPB + nn;
#pragma unroll
        for (int o = 0; o < 8; ++o) {
            int c0 = (o * 2 + half) * 8;       // octet of 8 channels
            unsigned vals[4];
#pragma unroll
            for (int j2 = 0; j2 < 4; ++j2) {
                float f0 = valid ? xbase[(size_t)(c0 + 2 * j2) * NPB] : 0.f;
                float f1 = valid ? xbase[(size_t)(c0 + 2 * j2 + 1) * NPB] : 0.f;
                vals[j2] = pack_bf16x2(f0, f1);
            }
            int byte = nl * 256 + ((c0 * 2) ^ ((nl & 7) << 4));
            *(uint4*)(&lds[XS_OFF + byte]) = make_uint4(vals[0], vals[1], vals[2], vals[3]);
        }
    }
    // ---- stage wt: W[c,col] -> wt[col][c] (bf16, swizzled)
    {
        const int col  = tid & 127;
        const int half = tid >> 7;
#pragma unroll
        for (int o = 0; o < 8; ++o) {
            int c0 = (o * 2 + half) * 8;
            unsigned vals[4];
#pragma unroll
            for (int j2 = 0; j2 < 4; ++j2) {
                float f0 = W[(size_t)(c0 + 2 * j2) * DMODEL + col];
                float f1 = W[(size_t)(c0 + 2 * j2 + 1) * DMODEL + col];
                vals[j2] = pack_bf16x2(f0, f1);
            }
            int byte = col * 256 + ((c0 * 2) ^ ((col & 7) << 4));
            *(uint4*)(&lds[WT_OFF + byte]) = make_uint4(vals[0], vals[1], vals[2], vals[3]);
        }
    }
    // denom zero (only the m==0 grid slice)
    if (m == 0) {
#pragma unroll
        for (int i = 0; i < 2; ++i) {
            int idx  = i * 256 + tid;          // 0..511
            int node = node0 + (idx >> 2);
            if (node < NB) denom[node * 4 + (idx & 3)] = 0.f;
        }
    }
    __syncthreads();

    // ---- MFMA: wave w computes nodes [w*32, w*32+32) x all 128 cols
    const int w    = tid >> 6;
    const int lane = tid & 63;
    const int rl   = lane & 15;
    const int g    = lane >> 4;

    f32x4 acc[2][8] = {};
#pragma unroll
    for (int ks = 0; ks < 4; ++ks) {
        const int kb2 = ks * 64 + g * 16;      // byte offset of this lane's k-octet
        bf16x8 a[2], b[8];
#pragma unroll
        for (int mt = 0; mt < 2; ++mt) {
            int row = w * 32 + mt * 16 + rl;
            a[mt] = *(const bf16x8*)(&lds[XS_OFF + row * 256 + (kb2 ^ ((row & 7) << 4))]);
        }
#pragma unroll
        for (int nt = 0; nt < 8; ++nt) {
            int colr = nt * 16 + rl;
            b[nt] = *(const bf16x8*)(&lds[WT_OFF + colr * 256 + (kb2 ^ ((colr & 7) << 4))]);
        }
#pragma unroll
        for (int mt = 0; mt < 2; ++mt)
#pragma unroll
            for (int nt = 0; nt < 8; ++nt)
                acc[mt][nt] = __builtin_amdgcn_mfma_f32_16x16x32_bf16(
                    a[mt], b[nt], acc[mt][nt], 0, 0, 0);
    }

    // ---- epilogue: D col = lane&15, row = (lane>>4)*4 + r
#pragma unroll
    for (int mt = 0; mt < 2; ++mt) {
        int nodeb = node0 + w * 32 + mt * 16 + g * 4;
#pragma unroll
        for (int nt = 0; nt < 8; ++nt) {
            int col = nt * 16 + rl;
            float bv_ = bi[col];
#pragma unroll
            for (int r = 0; r < 4; ++r) {
                int node = nodeb + r;
                if (node < NB) outp[(size_t)node * DMODEL + col] = acc[mt][nt][r] + bv_;
            }
        }
    }
}

// -------------------------------------------------------------------------
// Kernel 2: per-edge alpha -> ea = exp(alpha*scale), denom via atomics.
// -------------------------------------------------------------------------
__global__ __launch_bounds__(256) void k_alpha(
    const float* __restrict__ qb, const float* __restrict__ kb,
    const int*   __restrict__ eidx, const float* __restrict__ eattr,
    const float* __restrict__ We,
    float* __restrict__ ea_buf, float* __restrict__ denom)
{
    __shared__ float eas[64][36];
    __shared__ int   srcs[64], dsts[64];
    const int tid = threadIdx.x;
    const int t0  = blockIdx.x * 64;
    const int c   = tid & 127;

    float wer[32];
#pragma unroll
    for (int k = 0; k < EDIM; ++k) wer[k] = We[k * DMODEL + c];

#pragma unroll
    for (int it = 0; it < 8; ++it) {
        int linear = it * 256 + tid;
        eas[linear >> 5][linear & 31] = eattr[(size_t)t0 * EDIM + linear];
    }
    if (tid < 64) {
        int t = t0 + tid;
        int b = t / EPG;
        int e = t - b * EPG;
        srcs[tid] = eidx[(size_t)(b * 2) * EPG + e];
        dsts[tid] = eidx[(size_t)(b * 2 + 1) * EPG + e];
    }
    __syncthreads();

    const int g = tid >> 7;
    const int h = c >> 5;
    const int d = c & 31;

    for (int sub = 0; sub < 32; ++sub) {
        int slot = sub * 2 + g;
        int t = t0 + slot;
        float eacc = 0.f;
        const float4* er = (const float4*)eas[slot];
#pragma unroll
        for (int k4 = 0; k4 < 8; ++k4) {
            float4 ev = er[k4];
            eacc += ev.x * wer[4 * k4 + 0] + ev.y * wer[4 * k4 + 1]
                  + ev.z * wer[4 * k4 + 2] + ev.w * wer[4 * k4 + 3];
        }
        int sv = srcs[slot], dv = dsts[slot];
        float qv = qb[(size_t)dv * DMODEL + c];
        float kv = kb[(size_t)sv * DMODEL + c];
        float p = qv * (kv + eacc);
#pragma unroll
        for (int off = 16; off >= 1; off >>= 1) p += __shfl_xor(p, off, 64);
        float ea = __expf(p * 0.17677669529663689f);  // 1/sqrt(32)
        if (d == 0) {
            ea_buf[(size_t)t * 4 + h] = ea;
            unsafeAtomicAdd(&denom[dv * 4 + h], ea);
        }
    }
}

// -------------------------------------------------------------------------
// Kernel 3: per-edge weighted aggregation of (v[src]+e) into agg via atomics.
// -------------------------------------------------------------------------
__global__ __launch_bounds__(256) void k_aggr(
    const float* __restrict__ vb,
    const int*   __restrict__ eidx, const float* __restrict__ eattr,
    const float* __restrict__ We,
    const float* __restrict__ ea_buf, const float* __restrict__ denom,
    float* __restrict__ agg)
{
    __shared__ float eas[64][36];
    __shared__ int   srcs[64], dsts[64];
    const int tid = threadIdx.x;
    const int t0  = blockIdx.x * 64;
    const int c   = tid & 127;

    float wer[32];
#pragma unroll
    for (int k = 0; k < EDIM; ++k) wer[k] = We[k * DMODEL + c];

#pragma unroll
    for (int it = 0; it < 8; ++it) {
        int linear = it * 256 + tid;
        eas[linear >> 5][linear & 31] = eattr[(size_t)t0 * EDIM + linear];
    }
    if (tid < 64) {
        int t = t0 + tid;
        int b = t / EPG;
        int e = t - b * EPG;
        srcs[tid] = eidx[(size_t)(b * 2) * EPG + e];
        dsts[tid] = eidx[(size_t)(b * 2 + 1) * EPG + e];
    }
    __syncthreads();

    const int g = tid >> 7;
    const int h = c >> 5;

    for (int sub = 0; sub < 32; ++sub) {
        int slot = sub * 2 + g;
        int t = t0 + slot;
        float eacc = 0.f;
        const float4* er = (const float4*)eas[slot];
#pragma unroll
        for (int k4 = 0; k4 < 8; ++k4) {
            float4 ev = er[k4];
            eacc += ev.x * wer[4 * k4 + 0] + ev.y * wer[4 * k4 + 1]
                  + ev.z * wer[4 * k4 + 2] + ev.w * wer[4 * k4 + 3];
        }
        int sv = srcs[slot], dv = dsts[slot];
        float ea  = ea_buf[(size_t)t * 4 + h];
        float den = denom[dv * 4 + h];
        float w = ea / (den + 1e-16f);
        float vv = vb[(size_t)sv * DMODEL + c] + eacc;
        unsafeAtomicAdd(&agg[(size_t)dv * DMODEL + c], w * vv);
    }
}

// -------------------------------------------------------------------------
// Kernel 3.5: pre-pack W1^T and W2^T into MFMA A-fragment layout (bf16).
// w1f: 64 frags (m1 0..15, ks 0..3); w2f: 64 frags (m2 0..7, ks 0..7).
// Each frag = 64 lanes x 16B.  8192 threads total.
// -------------------------------------------------------------------------
__global__ __launch_bounds__(256) void k_prep(
    const float* __restrict__ W1, const float* __restrict__ W2,
    uint4* __restrict__ w1f, uint4* __restrict__ w2f)
{
    int t = blockIdx.x * 256 + threadIdx.x;   // 0..8191
    int lane = t & 63;
    int frag = t >> 6;                         // 0..127
    int rl = lane & 15, g = lane >> 4;
    unsigned v[4];
    if (frag < 64) {
        int m1 = frag >> 2, ks = frag & 3;
        int col1 = m1 * 16 + rl;
        int k0 = ks * 32 + g * 8;
#pragma unroll
        for (int j2 = 0; j2 < 4; ++j2) {
            float f0 = W1[(k0 + 2 * j2) * FFD + col1];
            float f1 = W1[(k0 + 2 * j2 + 1) * FFD + col1];
            v[j2] = pack_bf16x2(f0, f1);
        }
        w1f[frag * 64 + lane] = make_uint4(v[0], v[1], v[2], v[3]);
    } else {
        int f2 = frag - 64;
        int m2 = f2 >> 3, ks = f2 & 7;
        int c2 = m2 * 16 + rl;
        int k0 = ks * 32 + g * 8;
#pragma unroll
        for (int j2 = 0; j2 < 4; ++j2) {
            float f0 = W2[(k0 + 2 * j2) * DMODEL + c2];
            float f1 = W2[(k0 + 2 * j2 + 1) * DMODEL + c2];
            v[j2] = pack_bf16x2(f0, f1);
        }
        w2f[f2 * 64 + lane] = make_uint4(v[0], v[1], v[2], v[3]);
    }
}

// -------------------------------------------------------------------------
// Kernel 4 (MFMA): FFN.  64 nodes/block, 256 thr (4 waves).
// GEMM1 (swapped): D1[col1][node] = W1^T @ xs^T  -> h1 LDS (bf16 swz)
// GEMM2 (swapped): D2[c2][node]   = W2^T @ h1^T  -> transposed global write
// LDS: xs[64][128]bf16 swz @0 (16KB), h1[64][256]bf16 swz @16384 (32KB).
// -------------------------------------------------------------------------
#define H1_OFF 16384

__global__ __launch_bounds__(256) void k_ffn_mfma(
    const float* __restrict__ agg,
    const uint4* __restrict__ w1f, const float* __restrict__ b1,
    const uint4* __restrict__ w2f, const float* __restrict__ b2,
    float* __restrict__ out)
{
    __shared__ __align__(16) char lds[49152];
    const int tid   = threadIdx.x;
    const int node0 = blockIdx.x * 64;

    // ---- stage xs[row][c] bf16 swizzled from agg (fp32, coalesced)
#pragma unroll
    for (int i = 0; i < 8; ++i) {
        int linear = i * 256 + tid;            // 0..2047
        int row = linear >> 5;                 // 0..63
        int c4  = (linear & 31) * 4;           // 0..124
        int node = node0 + row;
        float4 f = (node < NB) ? *(const float4*)&agg[(size_t)node * DMODEL + c4]
                               : make_float4(0.f, 0.f, 0.f, 0.f);
        unsigned lo = pack_bf16x2(f.x, f.y), hi = pack_bf16x2(f.z, f.w);
        int byte = row * 256 + ((c4 * 2) ^ ((row & 7) << 4));
        *(uint2*)(&lds[byte]) = make_uint2(lo, hi);
    }
    __syncthreads();

    const int w = tid >> 6, lane = tid & 63;
    const int rl = lane & 15, g = lane >> 4;

    // ---- GEMM1: wave w covers col1 in [w*64, w*64+64)
    {
        f32x4 acc[4][4] = {};
#pragma unroll
        for (int ks = 0; ks < 4; ++ks) {
            bf16x8 a[4], b[4];
#pragma unroll
            for (int mt = 0; mt < 4; ++mt) {
                int m1 = w * 4 + mt;
                a[mt] = *(const bf16x8*)&w1f[(m1 * 4 + ks) * 64 + lane];
            }
#pragma unroll
            for (int nt = 0; nt < 4; ++nt) {
                int node = nt * 16 + rl;
                int byte = node * 256 + ((ks * 64 + g * 16) ^ ((node & 7) << 4));
                b[nt] = *(const bf16x8*)&lds[byte];
            }
#pragma unroll
            for (int mt = 0; mt < 4; ++mt)
#pragma unroll
                for (int nt = 0; nt < 4; ++nt)
                    acc[mt][nt] = __builtin_amdgcn_mfma_f32_16x16x32_bf16(
                        a[mt], b[nt], acc[mt][nt], 0, 0, 0);
        }
        // epilogue: +b1, relu, bf16-pack, ds_write_b64 into h1[node][col1]
#pragma unroll
        for (int mt = 0; mt < 4; ++mt) {
            int col1_0 = w * 64 + mt * 16 + g * 4;
            float bb0 = b1[col1_0], bb1 = b1[col1_0 + 1],
                  bb2 = b1[col1_0 + 2], bb3 = b1[col1_0 + 3];
#pragma unroll
            for (int nt = 0; nt < 4; ++nt) {
                int node = nt * 16 + rl;
                float v0 = fmaxf(acc[mt][nt][0] + bb0, 0.f);
                float v1 = fmaxf(acc[mt][nt][1] + bb1, 0.f);
                float v2 = fmaxf(acc[mt][nt][2] + bb2, 0.f);
                float v3 = fmaxf(acc[mt][nt][3] + bb3, 0.f);
                unsigned lo = pack_bf16x2(v0, v1), hi = pack_bf16x2(v2, v3);
                int byte = H1_OFF + node * 512 + ((col1_0 * 2) ^ ((node & 7) << 4));
                *(uint2*)(&lds[byte]) = make_uint2(lo, hi);
            }
        }
    }
    __syncthreads();

    // ---- GEMM2: wave w covers c2 in [w*32, w*32+32)
    {
        f32x4 acc[2][4] = {};
#pragma unroll
        for (int ks = 0; ks < 8; ++ks) {
            bf16x8 a[2], b[4];
#pragma unroll
            for (int mt = 0; mt < 2; ++mt) {
                int m2 = w * 2 + mt;
                a[mt] = *(const bf16x8*)&w2f[(m2 * 8 + ks) * 64 + lane];
            }
#pragma unroll
            for (int nt = 0; nt < 4; ++nt) {
                int node = nt * 16 + rl;
                int byte = H1_OFF + node * 512 + ((ks * 64 + g * 16) ^ ((node & 7) << 4));
                b[nt] = *(const bf16x8*)&lds[byte];
            }
#pragma unroll
            for (int mt = 0; mt < 2; ++mt)
#pragma unroll
                for (int nt = 0; nt < 4; ++nt)
                    acc[mt][nt] = __builtin_amdgcn_mfma_f32_16x16x32_bf16(
                        a[mt], b[nt], acc[mt][nt], 0, 0, 0);
        }
        // epilogue: +b2, relu, transposed global write out[b, c2, nn]
#pragma unroll
        for (int mt = 0; mt < 2; ++mt) {
            int c2_0 = w * 32 + mt * 16 + g * 4;
#pragma unroll
            for (int nt = 0; nt < 4; ++nt) {
                int node = node0 + nt * 16 + rl;
                if (node < NB) {
                    int bb = node / NPB;
                    int nn = node - bb * NPB;
                    size_t base = (size_t)(bb * DMODEL) * NPB + nn;
#pragma unroll
                    for (int r = 0; r < 4; ++r) {
                        float v = fmaxf(acc[mt][nt][r] + b2[c2_0 + r], 0.f);
                        out[base + (size_t)(c2_0 + r) * NPB] = v;
                    }
                }
            }
        }
    }
}

// -------------------------------------------------------------------------
extern "C" void kernel_launch(void* const* d_in, const int* in_sizes, int n_in,
                              void* d_out, int out_size, void* d_ws, size_t ws_size,
                              hipStream_t stream)
{
    const float* x     = (const float*)d_in[0];
    const int*   eidx  = (const int*)  d_in[1];
    const float* eattr = (const float*)d_in[2];
    const float* Wq    = (const float*)d_in[3];
    const float* bq    = (const float*)d_in[4];
    const float* Wk    = (const float*)d_in[5];
    const float* bk    = (const float*)d_in[6];
    const float* Wv    = (const float*)d_in[7];
    const float* bv    = (const float*)d_in[8];
    const float* We    = (const float*)d_in[9];
    const float* Wskip = (const float*)d_in[10];
    const float* bskip = (const float*)d_in[11];
    const float* W1    = (const float*)d_in[12];
    const float* b1    = (const float*)d_in[13];
    const float* W2    = (const float*)d_in[14];
    const float* b2    = (const float*)d_in[15];
    float* out = (float*)d_out;

    float* ws    = (float*)d_ws;
    float* qb    = ws;
    float* kb    = qb + (size_t)NB * DMODEL;
    float* vb    = kb + (size_t)NB * DMODEL;
    float* agg   = vb + (size_t)NB * DMODEL;
    float* ea_bf = agg + (size_t)NB * DMODEL;
    float* denom = ea_bf + (size_t)T_E * 4;

    // weight frags reuse the ea_bf region (dead after k_aggr; k_prep runs after)
    uint4* w1f = (uint4*)ea_bf;
    uint4* w2f = w1f + 4096;

    dim3 pgrid((NB + 127) / 128, 4);
    k_proj_mfma<<<pgrid, 256, 0, stream>>>(x, Wq, bq, Wk, bk, Wv, bv,
                                           Wskip, bskip, qb, kb, vb, agg, denom);
    k_alpha<<<T_E / 64, 256, 0, stream>>>(qb, kb, eidx, eattr, We, ea_bf, denom);
    k_aggr<<<T_E / 64, 256, 0, stream>>>(vb, eidx, eattr, We, ea_bf, denom, agg);
    k_prep<<<32, 256, 0, stream>>>(W1, W2, w1f, w2f);
    k_ffn_mfma<<<(NB + 63) / 64, 256, 0, stream>>>(agg, w1f, b1, w2f, b2, out);
}